// Round 5
// baseline (581.185 us; speedup 1.0000x reference)
//
#include <hip/hip_runtime.h>
#include <hip/hip_bf16.h>
#include <cstdint>
#include <cstddef>

// CascadeAttention MI355X — v4: catW transposed to [b][i][n] (all accesses
// lane-coalesced), packed-Q from dwconv, K/V-shared 2-group attention waves,
// double-buffered 64n-tile MFMA proj.

#define NH    8
#define KD    16
#define DV    32
#define CH    32
#define QKVO  64
#define DIMC  256
#define NTOK  392
#define NPAD  448
#define NN    (NTOK*NTOK)
#define BSZ   128
#define EPSV  1e-5f
#define SCL2  0.3606737602222409f   // 0.25 * log2(e)
#define LOG2E 1.4426950408889634f

typedef float f32x4 __attribute__((ext_vector_type(4)));
typedef short bf16x8 __attribute__((ext_vector_type(8)));
typedef unsigned int u32x4 __attribute__((ext_vector_type(4)));

__device__ inline unsigned rne_bf16_bits(float x) {
  unsigned u = __float_as_uint(x);
  return (u + 0x7fffu + ((u >> 16) & 1u)) >> 16;
}
__device__ inline unsigned pack_hilo(float v) {   // u32 = hi16 | lo16<<16
  unsigned u = __float_as_uint(v) & 0xffff0000u;
  float lo = v - __uint_as_float(u);
  return (u >> 16) | (rne_bf16_bits(lo) << 16);
}
__device__ inline float unpack_hilo(unsigned w) {
  return __uint_as_float(w << 16) + __uint_as_float(w & 0xffff0000u);
}

// ---------------- bias gather (pre-scaled by log2e) ------------------------
__global__ __launch_bounds__(256) void k_bias(const float* __restrict__ rpb,
                                              const int* __restrict__ rel,
                                              float* __restrict__ bias) {
  int t = blockIdx.x * 256 + threadIdx.x;
  if (t >= NH * NN) return;
  int h = t / NN;
  int pos = t - h * NN;
  bias[t] = rpb[rel[pos] * NH + h] * LOG2E;
}

// ---------------- proj weight hi/lo pre-split ------------------------------
__global__ __launch_bounds__(256) void k_wsplit(const float* __restrict__ W,
                                                short* __restrict__ Whi,
                                                short* __restrict__ Wlo) {
  int i = blockIdx.x * 256 + threadIdx.x;
  if (i >= DIMC * DIMC) return;
  float v = W[i];
  unsigned u = __float_as_uint(v) & 0xffff0000u;
  Whi[i] = (short)(u >> 16);
  Wlo[i] = (short)rne_bf16_bits(v - __uint_as_float(u));
}

// ---------------- qkv 1x1 conv + BN, emit MFMA-ready K/V -------------------
// catW now [b][i][n]: cascade reads coalesced along n.
__global__ __launch_bounds__(256) void k_qkv(int head,
    const float* __restrict__ x, const unsigned* __restrict__ catW,
    const float* __restrict__ W, const float* __restrict__ G,
    const float* __restrict__ Bp, const float* __restrict__ Mp,
    const float* __restrict__ Vp,
    float* __restrict__ qb, short* __restrict__ kT, short* __restrict__ vbB) {
  int t = threadIdx.x;
  int b = blockIdx.y;
  int n = blockIdx.x * 64 + (t & 63);
  int w = t >> 6;
  int o0 = __builtin_amdgcn_readfirstlane(w * 16);
  int nc = min(n, NTOK - 1);

  const float* xp = x + ((size_t)b * DIMC + head * CH) * NTOK + nc;
  float f[CH];
  if (head == 0) {
#pragma unroll
    for (int c = 0; c < CH; ++c) f[c] = xp[(size_t)c * NTOK];
  } else {
    const unsigned* cp = catW + ((size_t)b * DIMC + (head - 1) * DV) * NTOK + nc;
#pragma unroll
    for (int c = 0; c < CH; ++c)
      f[c] = xp[(size_t)c * NTOK] + unpack_hilo(cp[(size_t)c * NTOK]);
  }

  const float* wp = W + head * QKVO * CH;
  float acc[16];
#pragma unroll
  for (int oi = 0; oi < 16; ++oi) acc[oi] = 0.f;
#pragma unroll
  for (int c = 0; c < CH; ++c) {
    float fv = f[c];
#pragma unroll
    for (int oi = 0; oi < 16; ++oi) acc[oi] += wp[(o0 + oi) * CH + c] * fv;
  }
  float r[16];
#pragma unroll
  for (int oi = 0; oi < 16; ++oi) {
    int o = o0 + oi;
    float s = G[head * QKVO + o] * rsqrtf(Vp[head * QKVO + o] + EPSV);
    float sh = Bp[head * QKVO + o] - Mp[head * QKVO + o] * s;
    r[oi] = acc[oi] * s + sh;
  }

  if (w == 0) {                       // q fp32, [c][n]
    if (n < NTOK) {
#pragma unroll
      for (int oi = 0; oi < 16; ++oi)
        qb[((size_t)b * KD + oi) * NTOK + n] = r[oi];
    }
  } else if (w == 1) {                // K -> packed transposed row
    unsigned hi[16], lo[16];
#pragma unroll
    for (int i = 0; i < 16; ++i) {
      unsigned u = __float_as_uint(r[i]) & 0xffff0000u;
      hi[i] = u >> 16;
      lo[i] = rne_bf16_bits(r[i] - __uint_as_float(u));
    }
    unsigned kw[16];
#pragma unroll
    for (int j = 0; j < 8; ++j) {
      kw[j]     = hi[2 * j] | (hi[2 * j + 1] << 16);
      kw[8 + j] = lo[2 * j] | (lo[2 * j + 1] << 16);
    }
    short* row = kT + ((size_t)b * NPAD + n) * 32;
#pragma unroll
    for (int p = 0; p < 4; ++p)
      *(u32x4*)&row[p * 8] = (u32x4){kw[4*p], kw[4*p+1], kw[4*p+2], kw[4*p+3]};
  } else {                            // V bf16, [c][n]
    int vc0 = (w - 2) * 16;
#pragma unroll
    for (int oi = 0; oi < 16; ++oi)
      vbB[((size_t)b * DV + vc0 + oi) * NPAD + n] = (short)rne_bf16_bits(r[oi]);
  }
}

// ---------------- dwconv 3x3x3 + BN -> packed Q rows (SCL2 folded) ---------
// grid (7, B), 128 thr = 2 waves. Wave handles 64 tokens x 8 channels.
// LDS: q halo [16][180] + weights [16*27].
__global__ __launch_bounds__(128) void k_dwconv2(int head,
    const float* __restrict__ qb, const float* __restrict__ DW,
    const float* __restrict__ G, const float* __restrict__ Bp,
    const float* __restrict__ Mp, const float* __restrict__ Vp,
    short* __restrict__ qcT) {
  __shared__ float hs[16 * 180];
  __shared__ float wc[432];
  int t = threadIdx.x;
  int qt = blockIdx.x, b = blockIdx.y;
  int n0 = qt * 64;
  const float* qp = qb + (size_t)b * KD * NTOK;

  for (int i = t; i < 432; i += 128) wc[i] = DW[head * 432 + i];
#pragma unroll
  for (int c = 0; c < 16; ++c) {
    for (int r = t; r < 178; r += 128) {
      int n = n0 - 57 + r;
      hs[c * 180 + r] = (n >= 0 && n < NTOK) ? qp[(size_t)c * NTOK + n] : 0.f;
    }
  }
  __syncthreads();

  int n = n0 + (t & 63);
  int h8 = (t >> 6) * 8;
  if (n >= NTOK) return;
  int z = n / 49, rm = n - z * 49, y = rm / 7, xx = rm - y * 7;

  short hi8[8], lo8[8];
#pragma unroll
  for (int cc = 0; cc < 8; ++cc) {
    int c = h8 + cc;
    float a = 0.f;
#pragma unroll
    for (int dz = 0; dz < 3; ++dz) {
      int zz = z + dz - 1;
      if (zz < 0 || zz >= 8) continue;
#pragma unroll
      for (int dy = 0; dy < 3; ++dy) {
        int yy = y + dy - 1;
        if (yy < 0 || yy >= 7) continue;
#pragma unroll
        for (int dx = 0; dx < 3; ++dx) {
          int xw = xx + dx - 1;
          if (xw < 0 || xw >= 7) continue;
          int rel = zz * 49 + yy * 7 + xw - n0 + 57;
          a += wc[c * 27 + dz * 9 + dy * 3 + dx] * hs[c * 180 + rel];
        }
      }
    }
    float s = G[head * KD + c] * rsqrtf(Vp[head * KD + c] + EPSV);
    float sh = Bp[head * KD + c] - Mp[head * KD + c] * s;
    unsigned pw = pack_hilo((a * s + sh) * SCL2);
    hi8[cc] = (short)(pw & 0xffffu);
    lo8[cc] = (short)(pw >> 16);
  }
  short* row = qcT + ((size_t)b * NPAD + n) * 32;
  *(bf16x8*)&row[h8]      = *(bf16x8*)hi8;
  *(bf16x8*)&row[16 + h8] = *(bf16x8*)lo8;
}

// ---------------- attention v4: 2 q-groups/wave, shared K/V ----------------
// grid (7, B), 128 thr = 2 waves; wave owns 32 queries (groups A,B of 16).
__global__ __launch_bounds__(128) void k_attn5(int head,
    const short* __restrict__ qcT, const short* __restrict__ kT,
    const short* __restrict__ vbB, const float* __restrict__ bias,
    unsigned* __restrict__ catW) {
  __shared__ __align__(16) unsigned Pbuf[2][2][16 * 68];
  int t = threadIdx.x;
  int qt = blockIdx.x, b = blockIdx.y;
  int w = t >> 6, l = t & 63;
  int ln = l & 15, g = l >> 4;
  int tokA = qt * 64 + w * 32 + ln;
  int tokB = tokA + 16;
  int tcA = min(tokA, NTOK - 1), tcB = min(tokB, NTOK - 1);
  int koff = ((g >> 1) << 4) + ((g & 1) << 3);

  const short* qrA = qcT + ((size_t)b * NPAD + tcA) * 32;
  const short* qrB = qcT + ((size_t)b * NPAD + tcB) * 32;
  bf16x8 qA1 = *(const bf16x8*)&qrA[(g & 1) * 8];
  bf16x8 qB1 = *(const bf16x8*)&qrB[(g & 1) * 8];
  bf16x8 qA2, qB2;
  if (g < 2) {
    qA2 = *(const bf16x8*)&qrA[16 + (g & 1) * 8];
    qB2 = *(const bf16x8*)&qrB[16 + (g & 1) * 8];
  } else {
#pragma unroll
    for (int j = 0; j < 8; ++j) { qA2[j] = 0; qB2[j] = 0; }
  }

  const short* kbase = kT + (size_t)b * NPAD * 32;
  const short* vbase = vbB + (size_t)b * DV * NPAD;
  const float* bbA = bias + ((size_t)head * NTOK + tcA) * NTOK;
  const float* bbB = bias + ((size_t)head * NTOK + tcB) * NTOK;
  unsigned* pbA = &Pbuf[w][0][0];
  unsigned* pbB = &Pbuf[w][1][0];

  f32x4 oA[2], oB[2];
#pragma unroll
  for (int ct = 0; ct < 2; ++ct) {
    oA[ct] = (f32x4){0.f, 0.f, 0.f, 0.f};
    oB[ct] = (f32x4){0.f, 0.f, 0.f, 0.f};
  }
  float lsA = 0.f, lsB = 0.f;

  bf16x8 aK[4];
#pragma unroll
  for (int ms = 0; ms < 4; ++ms)
    aK[ms] = *(const bf16x8*)&kbase[(size_t)(16 * ms + ln) * 32 + koff];

#pragma unroll 1
  for (int mt = 0; mt < 7; ++mt) {
    int m0 = mt * 64;
    f32x4 bvA[4], bvB[4];
#pragma unroll
    for (int ms = 0; ms < 4; ++ms) {
      int col = min(m0 + 16 * ms + 4 * g, NTOK - 4);
      bvA[ms] = *(const f32x4*)&bbA[col];
      bvB[ms] = *(const f32x4*)&bbB[col];
    }
    bf16x8 aKn[4];
    int mn = (mt < 6) ? m0 + 64 : 0;
#pragma unroll
    for (int ms = 0; ms < 4; ++ms)
      aKn[ms] = *(const bf16x8*)&kbase[(size_t)(mn + 16 * ms + ln) * 32 + koff];
    // ---- QK^T (two independent chains share aK) ----
    f32x4 SA[4], SB[4];
#pragma unroll
    for (int ms = 0; ms < 4; ++ms) {
      f32x4 a = (f32x4){0.f, 0.f, 0.f, 0.f};
      a = __builtin_amdgcn_mfma_f32_16x16x32_bf16(aK[ms], qA1, a, 0, 0, 0);
      a = __builtin_amdgcn_mfma_f32_16x16x32_bf16(aK[ms], qA2, a, 0, 0, 0);
      SA[ms] = a;
      f32x4 c = (f32x4){0.f, 0.f, 0.f, 0.f};
      c = __builtin_amdgcn_mfma_f32_16x16x32_bf16(aK[ms], qB1, c, 0, 0, 0);
      c = __builtin_amdgcn_mfma_f32_16x16x32_bf16(aK[ms], qB2, c, 0, 0, 0);
      SB[ms] = c;
    }
    bf16x8 aV[4];
#pragma unroll
    for (int ch = 0; ch < 2; ++ch)
#pragma unroll
      for (int ct = 0; ct < 2; ++ct)
        aV[ch * 2 + ct] = *(const bf16x8*)&vbase[(size_t)(16 * ct + ln) * NPAD
                                                 + m0 + 32 * ch + 8 * g];
    // ---- p = exp2(s + bias), pack, stage ----
#pragma unroll
    for (int ms = 0; ms < 4; ++ms) {
      int mk = m0 + 16 * ms + 4 * g;
      u32x4 pwA, pwB;
#pragma unroll
      for (int r = 0; r < 4; ++r) {
        float sa = fminf(SA[ms][r] + bvA[ms][r], 96.f);
        float sb = fminf(SB[ms][r] + bvB[ms][r], 96.f);
        if (mk + r >= NTOK) { sa = -1e30f; sb = -1e30f; }
        float pa = __builtin_amdgcn_exp2f(sa);
        float pb = __builtin_amdgcn_exp2f(sb);
        lsA += pa; lsB += pb;
        pwA[r] = pack_hilo(pa);
        pwB[r] = pack_hilo(pb);
      }
      *(u32x4*)&pbA[ln * 68 + 16 * ms + 4 * g] = pwA;
      *(u32x4*)&pbB[ln * 68 + 16 * ms + 4 * g] = pwB;
    }
    // ---- PV ----
#pragma unroll
    for (int ch = 0; ch < 2; ++ch) {
      const unsigned* prA = &pbA[ln * 68 + 32 * ch + 8 * g];
      const unsigned* prB = &pbB[ln * 68 + 32 * ch + 8 * g];
      u32x4 a0 = *(const u32x4*)prA, a1 = *(const u32x4*)(prA + 4);
      u32x4 b0 = *(const u32x4*)prB, b1 = *(const u32x4*)(prB + 4);
      unsigned arrA[8] = {a0[0], a0[1], a0[2], a0[3], a1[0], a1[1], a1[2], a1[3]};
      unsigned arrB[8] = {b0[0], b0[1], b0[2], b0[3], b1[0], b1[1], b1[2], b1[3]};
      bf16x8 fhA, flA, fhB, flB;
#pragma unroll
      for (int j = 0; j < 8; ++j) {
        fhA[j] = (short)(arrA[j] & 0xffffu);  flA[j] = (short)(arrA[j] >> 16);
        fhB[j] = (short)(arrB[j] & 0xffffu);  flB[j] = (short)(arrB[j] >> 16);
      }
#pragma unroll
      for (int ct = 0; ct < 2; ++ct) {
        bf16x8 v = aV[ch * 2 + ct];
        oA[ct] = __builtin_amdgcn_mfma_f32_16x16x32_bf16(v, fhA, oA[ct], 0, 0, 0);
        oA[ct] = __builtin_amdgcn_mfma_f32_16x16x32_bf16(v, flA, oA[ct], 0, 0, 0);
        oB[ct] = __builtin_amdgcn_mfma_f32_16x16x32_bf16(v, fhB, oB[ct], 0, 0, 0);
        oB[ct] = __builtin_amdgcn_mfma_f32_16x16x32_bf16(v, flB, oB[ct], 0, 0, 0);
      }
    }
#pragma unroll
    for (int ms = 0; ms < 4; ++ms) aK[ms] = aKn[ms];
  }

  lsA += __shfl_xor(lsA, 16);  lsA += __shfl_xor(lsA, 32);
  lsB += __shfl_xor(lsB, 16);  lsB += __shfl_xor(lsB, 32);
  unsigned* cw = catW + (size_t)b * DIMC * NTOK + (size_t)head * DV * NTOK;
  if (tokA < NTOK) {
    float inv = 1.f / fmaxf(lsA, 1e-30f);
#pragma unroll
    for (int ct = 0; ct < 2; ++ct)
#pragma unroll
      for (int r = 0; r < 4; ++r)
        cw[(size_t)(16 * ct + 4 * g + r) * NTOK + tokA] = pack_hilo(oA[ct][r] * inv);
  }
  if (tokB < NTOK) {
    float inv = 1.f / fmaxf(lsB, 1e-30f);
#pragma unroll
    for (int ct = 0; ct < 2; ++ct)
#pragma unroll
      for (int r = 0; r < 4; ++r)
        cw[(size_t)(16 * ct + 4 * g + r) * NTOK + tokB] = pack_hilo(oB[ct][r] * inv);
  }
}

// ---------------- proj: 3-term hi/lo MFMA GEMM + BN, 64n, dbuf -------------
// grid (7, B), 256 thr; wave w -> o [64w,64w+64); B reads coalesced u32.
__global__ __launch_bounds__(256, 2) void k_proj4(const unsigned* __restrict__ catW,
    const short* __restrict__ Whi, const short* __restrict__ Wlo,
    const float* __restrict__ G, const float* __restrict__ Bp,
    const float* __restrict__ Mp, const float* __restrict__ Vp,
    float* __restrict__ out) {
  int t = threadIdx.x;
  int nt = blockIdx.x, b = blockIdx.y;
  int w = t >> 6, l = t & 63;
  int ln = l & 15, g = l >> 4;
  int n0 = nt * 64;
  int ntk[4];
#pragma unroll
  for (int ns = 0; ns < 4; ++ns) ntk[ns] = min(n0 + 16 * ns + ln, NTOK - 1);
  const unsigned* xb = catW + (size_t)b * DIMC * NTOK;

  f32x4 acc[4][4];
#pragma unroll
  for (int i = 0; i < 4; ++i)
#pragma unroll
    for (int j = 0; j < 4; ++j) acc[i][j] = (f32x4){0.f, 0.f, 0.f, 0.f};

  unsigned rb[4][8];
  bf16x8 wh[4], wl[4];
  {
    int c0 = 8 * g;
#pragma unroll
    for (int ns = 0; ns < 4; ++ns)
#pragma unroll
      for (int j = 0; j < 8; ++j)
        rb[ns][j] = xb[(size_t)(c0 + j) * NTOK + ntk[ns]];
#pragma unroll
    for (int ot = 0; ot < 4; ++ot) {
      size_t wo = (size_t)(64 * w + 16 * ot + ln) * DIMC + 8 * g;
      wh[ot] = *(const bf16x8*)&Whi[wo];
      wl[ot] = *(const bf16x8*)&Wlo[wo];
    }
  }

#pragma unroll 1
  for (int c8 = 0; c8 < 8; ++c8) {
    unsigned rbn[4][8];
    bf16x8 whn[4], wln[4];
    {
      int c0n = ((c8 + 1) & 7) * 32 + 8 * g;
#pragma unroll
      for (int ns = 0; ns < 4; ++ns)
#pragma unroll
        for (int j = 0; j < 8; ++j)
          rbn[ns][j] = xb[(size_t)(c0n + j) * NTOK + ntk[ns]];
#pragma unroll
      for (int ot = 0; ot < 4; ++ot) {
        size_t wo = (size_t)(64 * w + 16 * ot + ln) * DIMC + ((c8 + 1) & 7) * 32 + 8 * g;
        whn[ot] = *(const bf16x8*)&Whi[wo];
        wln[ot] = *(const bf16x8*)&Wlo[wo];
      }
    }
#pragma unroll
    for (int ns = 0; ns < 4; ++ns) {
      bf16x8 Bh, Bl;
#pragma unroll
      for (int j = 0; j < 8; ++j) {
        unsigned vv = rb[ns][j];
        vv = (vv & 0x8000u) ? 0u : vv;      // relu via hi sign bit
        Bh[j] = (short)(vv & 0xffffu);
        Bl[j] = (short)(vv >> 16);
      }
#pragma unroll
      for (int ot = 0; ot < 4; ++ot) {
        acc[ot][ns] = __builtin_amdgcn_mfma_f32_16x16x32_bf16(wh[ot], Bh, acc[ot][ns], 0, 0, 0);
        acc[ot][ns] = __builtin_amdgcn_mfma_f32_16x16x32_bf16(wh[ot], Bl, acc[ot][ns], 0, 0, 0);
        acc[ot][ns] = __builtin_amdgcn_mfma_f32_16x16x32_bf16(wl[ot], Bh, acc[ot][ns], 0, 0, 0);
      }
    }
#pragma unroll
    for (int ns = 0; ns < 4; ++ns)
#pragma unroll
      for (int j = 0; j < 8; ++j) rb[ns][j] = rbn[ns][j];
#pragma unroll
    for (int ot = 0; ot < 4; ++ot) { wh[ot] = whn[ot]; wl[ot] = wln[ot]; }
  }

#pragma unroll
  for (int ot = 0; ot < 4; ++ot)
#pragma unroll
    for (int r = 0; r < 4; ++r) {
      int o = 64 * w + 16 * ot + 4 * g + r;
      float s = G[o] * rsqrtf(Vp[o] + EPSV);
      float sh = Bp[o] - Mp[o] * s;
#pragma unroll
      for (int ns = 0; ns < 4; ++ns) {
        int n = n0 + 16 * ns + ln;
        if (n < NTOK)
          out[((size_t)b * DIMC + o) * NTOK + n] = acc[ot][ns][r] * s + sh;
      }
    }
}

// ---------------------------------------------------------------------------
extern "C" void kernel_launch(void* const* d_in, const int* in_sizes, int n_in,
                              void* d_out, int out_size, void* d_ws, size_t ws_size,
                              hipStream_t stream) {
  const float* x      = (const float*)d_in[0];
  const float* qkv_w  = (const float*)d_in[1];
  const float* qkv_g  = (const float*)d_in[2];
  const float* qkv_b  = (const float*)d_in[3];
  const float* qkv_m  = (const float*)d_in[4];
  const float* qkv_v  = (const float*)d_in[5];
  const float* dw_w   = (const float*)d_in[6];
  const float* dw_g   = (const float*)d_in[7];
  const float* dw_b   = (const float*)d_in[8];
  const float* dw_m   = (const float*)d_in[9];
  const float* dw_v   = (const float*)d_in[10];
  const float* proj_w = (const float*)d_in[11];
  const float* proj_g = (const float*)d_in[12];
  const float* proj_b = (const float*)d_in[13];
  const float* proj_m = (const float*)d_in[14];
  const float* proj_v = (const float*)d_in[15];
  const float* rpb    = (const float*)d_in[16];
  const int*   rel    = (const int*)d_in[17];
  float* out = (float*)d_out;

  // ws layout (float units), total ~17.70M f = 70.8 MB
  float* wsf  = (float*)d_ws;
  float*    bias = wsf;                                        // 1,229,312 f
  float*    qb   = bias + (size_t)NH * NN;                     //   802,816 f
  short*    qcT  = (short*)(qb + (size_t)BSZ * KD * NTOK);     // 1,835,008 sh
  short*    kT   = qcT + (size_t)BSZ * NPAD * 32;              // 1,835,008 sh
  short*    vbB  = kT  + (size_t)BSZ * NPAD * 32;              // 1,835,008 sh
  unsigned* catW = (unsigned*)(vbB + (size_t)BSZ * DV * NPAD); // 12,845,056 u32
  short*    Whi  = (short*)(catW + (size_t)BSZ * DIMC * NTOK); //    65,536 sh
  short*    Wlo  = Whi + (size_t)DIMC * DIMC;                  //    65,536 sh

  k_bias<<<dim3((NH * NN + 255) / 256), 256, 0, stream>>>(rpb, rel, bias);
  k_wsplit<<<dim3((DIMC * DIMC + 255) / 256), 256, 0, stream>>>(proj_w, Whi, Wlo);

  for (int h = 0; h < NH; ++h) {
    k_qkv<<<dim3(7, 128), 256, 0, stream>>>(h, x, catW, qkv_w, qkv_g, qkv_b,
                                            qkv_m, qkv_v, qb, kT, vbB);
    k_dwconv2<<<dim3(7, 128), 128, 0, stream>>>(h, qb, dw_w, dw_g, dw_b,
                                                dw_m, dw_v, qcT);
    k_attn5<<<dim3(7, 128), 128, 0, stream>>>(h, qcT, kT, vbB, bias, catW);
  }

  k_proj4<<<dim3(7, 128), 256, 0, stream>>>(catW, Whi, Wlo, proj_g, proj_b,
                                            proj_m, proj_v, out);
}

// Round 6
// 497.083 us; speedup vs baseline: 1.1692x; 1.1692x over previous
//
#include <hip/hip_runtime.h>
#include <hip/hip_bf16.h>
#include <cstdint>
#include <cstddef>

// CascadeAttention MI355X — v5: catW [b][i][n] coalesced everywhere,
// 4-way key-split attention (16q x 4 waves, LDS merge of no-max partials),
// v0-style dwconv (max blocks), double-buffered MFMA proj.

#define NH    8
#define KD    16
#define DV    32
#define CH    32
#define QKVO  64
#define DIMC  256
#define NTOK  392
#define NPAD  448
#define NN    (NTOK*NTOK)
#define BSZ   128
#define EPSV  1e-5f
#define SCL2  0.3606737602222409f   // 0.25 * log2(e)
#define LOG2E 1.4426950408889634f

typedef float f32x4 __attribute__((ext_vector_type(4)));
typedef short bf16x8 __attribute__((ext_vector_type(8)));
typedef unsigned int u32x4 __attribute__((ext_vector_type(4)));

__device__ inline unsigned rne_bf16_bits(float x) {
  unsigned u = __float_as_uint(x);
  return (u + 0x7fffu + ((u >> 16) & 1u)) >> 16;
}
__device__ inline unsigned pack_hilo(float v) {   // u32 = hi16 | lo16<<16
  unsigned u = __float_as_uint(v) & 0xffff0000u;
  float lo = v - __uint_as_float(u);
  return (u >> 16) | (rne_bf16_bits(lo) << 16);
}
__device__ inline float unpack_hilo(unsigned w) {
  return __uint_as_float(w << 16) + __uint_as_float(w & 0xffff0000u);
}

// ---------------- bias gather (pre-scaled by log2e) ------------------------
__global__ __launch_bounds__(256) void k_bias(const float* __restrict__ rpb,
                                              const int* __restrict__ rel,
                                              float* __restrict__ bias) {
  int t = blockIdx.x * 256 + threadIdx.x;
  if (t >= NH * NN) return;
  int h = t / NN;
  int pos = t - h * NN;
  bias[t] = rpb[rel[pos] * NH + h] * LOG2E;
}

// ---------------- proj weight hi/lo pre-split ------------------------------
__global__ __launch_bounds__(256) void k_wsplit(const float* __restrict__ W,
                                                short* __restrict__ Whi,
                                                short* __restrict__ Wlo) {
  int i = blockIdx.x * 256 + threadIdx.x;
  if (i >= DIMC * DIMC) return;
  float v = W[i];
  unsigned u = __float_as_uint(v) & 0xffff0000u;
  Whi[i] = (short)(u >> 16);
  Wlo[i] = (short)rne_bf16_bits(v - __uint_as_float(u));
}

// ---------------- qkv 1x1 conv + BN, emit MFMA-ready K/V -------------------
// catW [b][i][n]: cascade reads coalesced along n (lane = n).
__global__ __launch_bounds__(256) void k_qkv(int head,
    const float* __restrict__ x, const unsigned* __restrict__ catW,
    const float* __restrict__ W, const float* __restrict__ G,
    const float* __restrict__ Bp, const float* __restrict__ Mp,
    const float* __restrict__ Vp,
    float* __restrict__ qb, short* __restrict__ kT, short* __restrict__ vbB) {
  int t = threadIdx.x;
  int b = blockIdx.y;
  int n = blockIdx.x * 64 + (t & 63);
  int w = t >> 6;
  int o0 = __builtin_amdgcn_readfirstlane(w * 16);
  int nc = min(n, NTOK - 1);

  const float* xp = x + ((size_t)b * DIMC + head * CH) * NTOK + nc;
  float f[CH];
  if (head == 0) {
#pragma unroll
    for (int c = 0; c < CH; ++c) f[c] = xp[(size_t)c * NTOK];
  } else {
    const unsigned* cp = catW + ((size_t)b * DIMC + (head - 1) * DV) * NTOK + nc;
#pragma unroll
    for (int c = 0; c < CH; ++c)
      f[c] = xp[(size_t)c * NTOK] + unpack_hilo(cp[(size_t)c * NTOK]);
  }

  const float* wp = W + head * QKVO * CH;
  float acc[16];
#pragma unroll
  for (int oi = 0; oi < 16; ++oi) acc[oi] = 0.f;
#pragma unroll
  for (int c = 0; c < CH; ++c) {
    float fv = f[c];
#pragma unroll
    for (int oi = 0; oi < 16; ++oi) acc[oi] += wp[(o0 + oi) * CH + c] * fv;
  }
  float r[16];
#pragma unroll
  for (int oi = 0; oi < 16; ++oi) {
    int o = o0 + oi;
    float s = G[head * QKVO + o] * rsqrtf(Vp[head * QKVO + o] + EPSV);
    float sh = Bp[head * QKVO + o] - Mp[head * QKVO + o] * s;
    r[oi] = acc[oi] * s + sh;
  }

  if (w == 0) {                       // q fp32, [c][n]
    if (n < NTOK) {
#pragma unroll
      for (int oi = 0; oi < 16; ++oi)
        qb[((size_t)b * KD + oi) * NTOK + n] = r[oi];
    }
  } else if (w == 1) {                // K -> packed transposed row
    unsigned hi[16], lo[16];
#pragma unroll
    for (int i = 0; i < 16; ++i) {
      unsigned u = __float_as_uint(r[i]) & 0xffff0000u;
      hi[i] = u >> 16;
      lo[i] = rne_bf16_bits(r[i] - __uint_as_float(u));
    }
    unsigned kw[16];
#pragma unroll
    for (int j = 0; j < 8; ++j) {
      kw[j]     = hi[2 * j] | (hi[2 * j + 1] << 16);
      kw[8 + j] = lo[2 * j] | (lo[2 * j + 1] << 16);
    }
    short* row = kT + ((size_t)b * NPAD + n) * 32;
#pragma unroll
    for (int p = 0; p < 4; ++p)
      *(u32x4*)&row[p * 8] = (u32x4){kw[4*p], kw[4*p+1], kw[4*p+2], kw[4*p+3]};
  } else {                            // V bf16, [c][n]
    int vc0 = (w - 2) * 16;
#pragma unroll
    for (int oi = 0; oi < 16; ++oi)
      vbB[((size_t)b * DV + vc0 + oi) * NPAD + n] = (short)rne_bf16_bits(r[oi]);
  }
}

// ---------------- depthwise 3x3x3 conv + BN (v0 style, max blocks) ---------
__global__ __launch_bounds__(128) void k_dwconv(int head,
    const float* __restrict__ qb, const float* __restrict__ DW,
    const float* __restrict__ G, const float* __restrict__ Bp,
    const float* __restrict__ Mp, const float* __restrict__ Vp,
    float* __restrict__ qc) {
  __shared__ float qs[NTOK];
  __shared__ float wc[27];
  int c = blockIdx.x, b = blockIdx.y;
  int t = threadIdx.x;
  const float* qp = qb + ((size_t)b * KD + c) * NTOK;
  for (int i = t; i < NTOK; i += 128) qs[i] = qp[i];
  if (t < 27) wc[t] = DW[(head * KD + c) * 27 + t];
  __syncthreads();
  float s = G[head * KD + c] * rsqrtf(Vp[head * KD + c] + EPSV);
  float sh = Bp[head * KD + c] - Mp[head * KD + c] * s;
  for (int n = t; n < NTOK; n += 128) {
    int z = n / 49, r = n - z * 49, y = r / 7, xx = r - y * 7;
    float a = 0.f;
#pragma unroll
    for (int dz = 0; dz < 3; ++dz) {
      int zz = z + dz - 1;
      if (zz < 0 || zz >= 8) continue;
#pragma unroll
      for (int dy = 0; dy < 3; ++dy) {
        int yy = y + dy - 1;
        if (yy < 0 || yy >= 7) continue;
#pragma unroll
        for (int dx = 0; dx < 3; ++dx) {
          int xw = xx + dx - 1;
          if (xw < 0 || xw >= 7) continue;
          a += wc[dz * 9 + dy * 3 + dx] * qs[zz * 49 + yy * 7 + xw];
        }
      }
    }
    qc[((size_t)b * KD + c) * NTOK + n] = a * s + sh;
  }
}

// ---------------- attention v5: 4-way key split + LDS merge ----------------
// grid (25, B), 256 thr = 4 waves, all waves share the block's 16 queries;
// wave w handles m-tiles {w, w+4}. No-max exp2 softmax -> partials combine
// as o = sum(o_w) / sum(l_w). One __syncthreads, wave 0 merges + stores.
__global__ __launch_bounds__(256) void k_attn6(int head,
    const float* __restrict__ qc, const short* __restrict__ kT,
    const short* __restrict__ vbB, const float* __restrict__ bias,
    unsigned* __restrict__ catW) {
  __shared__ __align__(16) unsigned Pbuf[4][16 * 68];
  __shared__ float oM[4][2][16][16];   // [w][ct][4g+r][ln]
  __shared__ float lM[4][16];
  int t = threadIdx.x;
  int qt = blockIdx.x, b = blockIdx.y;
  int w = t >> 6, l = t & 63;
  int ln = l & 15, g = l >> 4;
  int tok = qt * 16 + ln;
  int tokc = min(tok, NTOK - 1);

  // Q frag (scaled, hi/lo) — strided gather, coalesced across 16 lanes
  bf16x8 qB1, qB2;
  {
    const float* qp = qc + (size_t)b * KD * NTOK + tokc;
    int c0 = 8 * (g & 1);
#pragma unroll
    for (int j = 0; j < 8; ++j) {
      float q = qp[(size_t)(c0 + j) * NTOK] * SCL2;
      unsigned u = __float_as_uint(q) & 0xffff0000u;
      qB1[j] = (short)(u >> 16);
      qB2[j] = (g < 2) ? (short)rne_bf16_bits(q - __uint_as_float(u)) : (short)0;
    }
  }

  const short* kbase = kT + (size_t)b * NPAD * 32;
  const short* vbase = vbB + (size_t)b * DV * NPAD;
  const float* bbase = bias + ((size_t)head * NTOK + tokc) * NTOK;
  unsigned* pb = &Pbuf[w][0];
  int koff = ((g >> 1) << 4) + ((g & 1) << 3);

  f32x4 oacc[2];
#pragma unroll
  for (int ct = 0; ct < 2; ++ct) oacc[ct] = (f32x4){0.f, 0.f, 0.f, 0.f};
  float lsum = 0.f;

  for (int mt = w; mt < 7; mt += 4) {
    int m0 = mt * 64;
    // loads first: K frags, bias row segs, V frags
    bf16x8 aK[4];
#pragma unroll
    for (int ms = 0; ms < 4; ++ms)
      aK[ms] = *(const bf16x8*)&kbase[(size_t)(m0 + 16 * ms + ln) * 32 + koff];
    f32x4 bv[4];
#pragma unroll
    for (int ms = 0; ms < 4; ++ms)
      bv[ms] = *(const f32x4*)&bbase[min(m0 + 16 * ms + 4 * g, NTOK - 4)];
    bf16x8 aV[4];
#pragma unroll
    for (int ch = 0; ch < 2; ++ch)
#pragma unroll
      for (int ct = 0; ct < 2; ++ct)
        aV[ch * 2 + ct] = *(const bf16x8*)&vbase[(size_t)(16 * ct + ln) * NPAD
                                                 + m0 + 32 * ch + 8 * g];
    // ---- QK^T ----
    f32x4 S[4];
#pragma unroll
    for (int ms = 0; ms < 4; ++ms) {
      f32x4 a = (f32x4){0.f, 0.f, 0.f, 0.f};
      a = __builtin_amdgcn_mfma_f32_16x16x32_bf16(aK[ms], qB1, a, 0, 0, 0);
      a = __builtin_amdgcn_mfma_f32_16x16x32_bf16(aK[ms], qB2, a, 0, 0, 0);
      S[ms] = a;
    }
    // ---- p = exp2(s + bias), pack, stage ----
#pragma unroll
    for (int ms = 0; ms < 4; ++ms) {
      int mk = m0 + 16 * ms + 4 * g;
      u32x4 pw;
#pragma unroll
      for (int r = 0; r < 4; ++r) {
        float s = fminf(S[ms][r] + bv[ms][r], 96.f);
        if (mk + r >= NTOK) s = -1e30f;
        float p = __builtin_amdgcn_exp2f(s);
        lsum += p;
        pw[r] = pack_hilo(p);
      }
      *(u32x4*)&pb[ln * 68 + 16 * ms + 4 * g] = pw;
    }
    // ---- PV ----
#pragma unroll
    for (int ch = 0; ch < 2; ++ch) {
      const unsigned* pr = &pb[ln * 68 + 32 * ch + 8 * g];
      u32x4 pa = *(const u32x4*)pr;
      u32x4 pc = *(const u32x4*)(pr + 4);
      unsigned arr[8] = {pa[0], pa[1], pa[2], pa[3], pc[0], pc[1], pc[2], pc[3]};
      bf16x8 fhi, flo;
#pragma unroll
      for (int j = 0; j < 8; ++j) {
        fhi[j] = (short)(arr[j] & 0xffffu);
        flo[j] = (short)(arr[j] >> 16);
      }
#pragma unroll
      for (int ct = 0; ct < 2; ++ct) {
        oacc[ct] = __builtin_amdgcn_mfma_f32_16x16x32_bf16(aV[ch * 2 + ct], fhi, oacc[ct], 0, 0, 0);
        oacc[ct] = __builtin_amdgcn_mfma_f32_16x16x32_bf16(aV[ch * 2 + ct], flo, oacc[ct], 0, 0, 0);
      }
    }
  }

  // ---- partial reduce + merge ----
  lsum += __shfl_xor(lsum, 16);
  lsum += __shfl_xor(lsum, 32);
#pragma unroll
  for (int ct = 0; ct < 2; ++ct)
#pragma unroll
    for (int r = 0; r < 4; ++r) oM[w][ct][4 * g + r][ln] = oacc[ct][r];
  if (g == 0) lM[w][ln] = lsum;
  __syncthreads();
  if (w == 0 && tok < NTOK) {
    float lt = lM[0][ln] + lM[1][ln] + lM[2][ln] + lM[3][ln];
    float inv = 1.f / fmaxf(lt, 1e-30f);
    unsigned* cw = catW + (size_t)b * DIMC * NTOK + (size_t)head * DV * NTOK;
#pragma unroll
    for (int ct = 0; ct < 2; ++ct)
#pragma unroll
      for (int r = 0; r < 4; ++r) {
        int c = 16 * ct + 4 * g + r;
        float o = oM[0][ct][4 * g + r][ln] + oM[1][ct][4 * g + r][ln]
                + oM[2][ct][4 * g + r][ln] + oM[3][ct][4 * g + r][ln];
        cw[(size_t)c * NTOK + tok] = pack_hilo(o * inv);
      }
  }
}

// ---------------- proj: 3-term hi/lo MFMA GEMM + BN, 64n, dbuf -------------
__global__ __launch_bounds__(256, 2) void k_proj4(const unsigned* __restrict__ catW,
    const short* __restrict__ Whi, const short* __restrict__ Wlo,
    const float* __restrict__ G, const float* __restrict__ Bp,
    const float* __restrict__ Mp, const float* __restrict__ Vp,
    float* __restrict__ out) {
  int t = threadIdx.x;
  int nt = blockIdx.x, b = blockIdx.y;
  int w = t >> 6, l = t & 63;
  int ln = l & 15, g = l >> 4;
  int n0 = nt * 64;
  int ntk[4];
#pragma unroll
  for (int ns = 0; ns < 4; ++ns) ntk[ns] = min(n0 + 16 * ns + ln, NTOK - 1);
  const unsigned* xb = catW + (size_t)b * DIMC * NTOK;

  f32x4 acc[4][4];
#pragma unroll
  for (int i = 0; i < 4; ++i)
#pragma unroll
    for (int j = 0; j < 4; ++j) acc[i][j] = (f32x4){0.f, 0.f, 0.f, 0.f};

  unsigned rb[4][8];
  bf16x8 wh[4], wl[4];
  {
    int c0 = 8 * g;
#pragma unroll
    for (int ns = 0; ns < 4; ++ns)
#pragma unroll
      for (int j = 0; j < 8; ++j)
        rb[ns][j] = xb[(size_t)(c0 + j) * NTOK + ntk[ns]];
#pragma unroll
    for (int ot = 0; ot < 4; ++ot) {
      size_t wo = (size_t)(64 * w + 16 * ot + ln) * DIMC + 8 * g;
      wh[ot] = *(const bf16x8*)&Whi[wo];
      wl[ot] = *(const bf16x8*)&Wlo[wo];
    }
  }

#pragma unroll 1
  for (int c8 = 0; c8 < 8; ++c8) {
    unsigned rbn[4][8];
    bf16x8 whn[4], wln[4];
    {
      int c0n = ((c8 + 1) & 7) * 32 + 8 * g;
#pragma unroll
      for (int ns = 0; ns < 4; ++ns)
#pragma unroll
        for (int j = 0; j < 8; ++j)
          rbn[ns][j] = xb[(size_t)(c0n + j) * NTOK + ntk[ns]];
#pragma unroll
      for (int ot = 0; ot < 4; ++ot) {
        size_t wo = (size_t)(64 * w + 16 * ot + ln) * DIMC + ((c8 + 1) & 7) * 32 + 8 * g;
        whn[ot] = *(const bf16x8*)&Whi[wo];
        wln[ot] = *(const bf16x8*)&Wlo[wo];
      }
    }
#pragma unroll
    for (int ns = 0; ns < 4; ++ns) {
      bf16x8 Bh, Bl;
#pragma unroll
      for (int j = 0; j < 8; ++j) {
        unsigned vv = rb[ns][j];
        vv = (vv & 0x8000u) ? 0u : vv;      // relu via hi sign bit
        Bh[j] = (short)(vv & 0xffffu);
        Bl[j] = (short)(vv >> 16);
      }
#pragma unroll
      for (int ot = 0; ot < 4; ++ot) {
        acc[ot][ns] = __builtin_amdgcn_mfma_f32_16x16x32_bf16(wh[ot], Bh, acc[ot][ns], 0, 0, 0);
        acc[ot][ns] = __builtin_amdgcn_mfma_f32_16x16x32_bf16(wh[ot], Bl, acc[ot][ns], 0, 0, 0);
        acc[ot][ns] = __builtin_amdgcn_mfma_f32_16x16x32_bf16(wl[ot], Bh, acc[ot][ns], 0, 0, 0);
      }
    }
#pragma unroll
    for (int ns = 0; ns < 4; ++ns)
#pragma unroll
      for (int j = 0; j < 8; ++j) rb[ns][j] = rbn[ns][j];
#pragma unroll
    for (int ot = 0; ot < 4; ++ot) { wh[ot] = whn[ot]; wl[ot] = wln[ot]; }
  }

#pragma unroll
  for (int ot = 0; ot < 4; ++ot)
#pragma unroll
    for (int r = 0; r < 4; ++r) {
      int o = 64 * w + 16 * ot + 4 * g + r;
      float s = G[o] * rsqrtf(Vp[o] + EPSV);
      float sh = Bp[o] - Mp[o] * s;
#pragma unroll
      for (int ns = 0; ns < 4; ++ns) {
        int n = n0 + 16 * ns + ln;
        if (n < NTOK)
          out[((size_t)b * DIMC + o) * NTOK + n] = acc[ot][ns][r] * s + sh;
      }
    }
}

// ---------------------------------------------------------------------------
extern "C" void kernel_launch(void* const* d_in, const int* in_sizes, int n_in,
                              void* d_out, int out_size, void* d_ws, size_t ws_size,
                              hipStream_t stream) {
  const float* x      = (const float*)d_in[0];
  const float* qkv_w  = (const float*)d_in[1];
  const float* qkv_g  = (const float*)d_in[2];
  const float* qkv_b  = (const float*)d_in[3];
  const float* qkv_m  = (const float*)d_in[4];
  const float* qkv_v  = (const float*)d_in[5];
  const float* dw_w   = (const float*)d_in[6];
  const float* dw_g   = (const float*)d_in[7];
  const float* dw_b   = (const float*)d_in[8];
  const float* dw_m   = (const float*)d_in[9];
  const float* dw_v   = (const float*)d_in[10];
  const float* proj_w = (const float*)d_in[11];
  const float* proj_g = (const float*)d_in[12];
  const float* proj_b = (const float*)d_in[13];
  const float* proj_m = (const float*)d_in[14];
  const float* proj_v = (const float*)d_in[15];
  const float* rpb    = (const float*)d_in[16];
  const int*   rel    = (const int*)d_in[17];
  float* out = (float*)d_out;

  // ws layout (float units), ~70.3 MB
  float* wsf  = (float*)d_ws;
  float*    bias = wsf;                                        // 1,229,312 f
  float*    qb   = bias + (size_t)NH * NN;                     //   802,816 f
  float*    qcb  = qb   + (size_t)BSZ * KD * NTOK;             //   802,816 f
  short*    kT   = (short*)(qcb + (size_t)BSZ * KD * NTOK);    // 1,835,008 sh
  short*    vbB  = kT + (size_t)BSZ * NPAD * 32;               // 1,835,008 sh
  unsigned* catW = (unsigned*)(vbB + (size_t)BSZ * DV * NPAD); // 12,845,056 u32
  short*    Whi  = (short*)(catW + (size_t)BSZ * DIMC * NTOK); //    65,536 sh
  short*    Wlo  = Whi + (size_t)DIMC * DIMC;                  //    65,536 sh

  k_bias<<<dim3((NH * NN + 255) / 256), 256, 0, stream>>>(rpb, rel, bias);
  k_wsplit<<<dim3((DIMC * DIMC + 255) / 256), 256, 0, stream>>>(proj_w, Whi, Wlo);

  for (int h = 0; h < NH; ++h) {
    k_qkv<<<dim3(7, 128), 256, 0, stream>>>(h, x, catW, qkv_w, qkv_g, qkv_b,
                                            qkv_m, qkv_v, qb, kT, vbB);
    k_dwconv<<<dim3(16, 128), 128, 0, stream>>>(h, qb, dw_w, dw_g, dw_b,
                                                dw_m, dw_v, qcb);
    k_attn6<<<dim3(25, 128), 256, 0, stream>>>(h, qcb, kT, vbB, bias, catW);
  }

  k_proj4<<<dim3(7, 128), 256, 0, stream>>>(catW, Whi, Wlo, proj_g, proj_b,
                                            proj_m, proj_v, out);
}